// Round 10
// baseline (140.341 us; speedup 1.0000x reference)
//
#include <hip/hip_runtime.h>
#include <hip/hip_bf16.h>

typedef short bf16x8 __attribute__((ext_vector_type(8)));
typedef float f32x4 __attribute__((ext_vector_type(4)));

constexpr int Nn = 65536;
constexpr int Kk = 256;
constexpr int Dd = 512;
constexpr int BM = 64;
constexpr int BK = 64;

static __device__ __forceinline__ unsigned short f2bf(float f) {
  __hip_bfloat16 h = __float2bfloat16(f);
  return *reinterpret_cast<unsigned short*>(&h);
}

static __device__ __forceinline__ void fence() { asm volatile("" ::: "memory"); }

// LDS-visibility-only barrier: vmcnt NOT drained.
static __device__ __forceinline__ void rbar() {
  asm volatile("s_waitcnt lgkmcnt(0)" ::: "memory");
  __builtin_amdgcn_s_barrier();
  fence();
}

// ---------------- prep: clusters -> bf16 + c2 ----------------
__global__ __launch_bounds__(64)
void prep_clusters_kernel(const float* __restrict__ C,
                          unsigned short* __restrict__ CB,
                          float* __restrict__ c2) {
  const int k = blockIdx.x;
  const int t = threadIdx.x;
  const float* row = C + (size_t)k * Dd;
  float4 a = *reinterpret_cast<const float4*>(row + t * 8);
  float4 b = *reinterpret_cast<const float4*>(row + t * 8 + 4);
  float s = a.x * a.x + a.y * a.y + a.z * a.z + a.w * a.w
          + b.x * b.x + b.y * b.y + b.z * b.z + b.w * b.w;
  uint4 p;
  p.x = ((unsigned)f2bf(a.y) << 16) | f2bf(a.x);
  p.y = ((unsigned)f2bf(a.w) << 16) | f2bf(a.z);
  p.z = ((unsigned)f2bf(b.y) << 16) | f2bf(b.x);
  p.w = ((unsigned)f2bf(b.w) << 16) | f2bf(b.z);
  *reinterpret_cast<uint4*>(CB + (size_t)k * Dd + t * 8) = p;
  #pragma unroll
  for (int m = 1; m < 64; m <<= 1) s += __shfl_xor(s, m, 64);
  if (t == 0) c2[k] = s;
}

// ---------------- PROBE 1: A global-load stream only ----------------
__global__ __launch_bounds__(256, 2)
void probe_g(const float* __restrict__ X, float* __restrict__ sink) {
  const int tid = threadIdx.x;
  const int rbase = blockIdx.x * BM;
  const int arow = tid >> 4;
  float4 v[2][4];
  float chk = 0.f;
  auto loadG = [&](int ks) {
    #pragma unroll
    for (int it = 0; it < 4; ++it)
      v[ks & 1][it] = *reinterpret_cast<const float4*>(
          &X[(size_t)(rbase + it * 16 + arow) * Dd + ks * BK + (tid & 15) * 4]);
  };
  loadG(0); loadG(1);
  #pragma unroll
  for (int ks = 0; ks < 8; ++ks) {
    #pragma unroll
    for (int it = 0; it < 4; ++it) {
      float4 f = v[ks & 1][it];
      chk += f.x * f.x + f.y * f.y + f.z * f.z + f.w * f.w;
    }
    if (ks < 6) loadG(ks + 2);
    rbar();
  }
  #pragma unroll
  for (int m = 1; m < 64; m <<= 1) chk += __shfl_xor(chk, m, 64);
  if ((tid & 63) == 0) sink[blockIdx.x * 4 + (tid >> 6)] = chk;
}

// ---------------- PROBE 2: full A path (load+cvt+ds_write+ds_read) ----------------
__global__ __launch_bounds__(256, 2)
void probe_a(const float* __restrict__ X, float* __restrict__ sink) {
  __shared__ __align__(16) char Al[2][BM * BK * 2];
  const int tid  = threadIdx.x;
  const int lane = tid & 63;
  const int hi   = lane >> 4;
  const int lo   = lane & 15;
  const int rbase = blockIdx.x * BM;
  const int arow  = tid >> 4;
  const int acolb = (tid & 15) * 8;
  float x2p[4] = {0.f, 0.f, 0.f, 0.f};
  float4 v[2][4];
  float chk = 0.f;
  auto loadG = [&](int ks) {
    #pragma unroll
    for (int it = 0; it < 4; ++it)
      v[ks & 1][it] = *reinterpret_cast<const float4*>(
          &X[(size_t)(rbase + it * 16 + arow) * Dd + ks * BK + (tid & 15) * 4]);
  };
  auto stage = [&](int ks) {
    #pragma unroll
    for (int it = 0; it < 4; ++it) {
      const int row = it * 16 + arow;
      float4 f = v[ks & 1][it];
      x2p[it] += f.x * f.x + f.y * f.y + f.z * f.z + f.w * f.w;
      uint2 p;
      p.x = ((unsigned)f2bf(f.y) << 16) | f2bf(f.x);
      p.y = ((unsigned)f2bf(f.w) << 16) | f2bf(f.z);
      const int addr = (row * 128 + acolb) ^ ((row & 7) << 4);
      *reinterpret_cast<uint2*>(&Al[ks & 1][addr]) = p;
    }
  };
  loadG(0);
  stage(0);
  loadG(1);
  rbar();
  #pragma unroll
  for (int ks = 0; ks < 8; ++ks) {
    if (ks < 7) stage(ks + 1);
    if (ks < 6) loadG(ks + 2);
    // compute-side swizzled ds_read_b128 x8, consumed by cheap VALU
    #pragma unroll
    for (int ku = 0; ku < 2; ++ku)
      #pragma unroll
      for (int m = 0; m < 4; ++m) {
        const int row = m * 16 + lo;
        const int addr = (row * 128 + ku * 64 + hi * 16) ^ ((row & 7) << 4);
        uint4 u = *reinterpret_cast<const uint4*>(&Al[ks & 1][addr]);
        chk += (float)(u.x ^ u.y ^ u.z ^ u.w);
      }
    rbar();
  }
  chk += x2p[0] + x2p[1] + x2p[2] + x2p[3];
  #pragma unroll
  for (int m = 1; m < 64; m <<= 1) chk += __shfl_xor(chk, m, 64);
  if ((tid & 63) == 0) sink[blockIdx.x * 4 + (tid >> 6)] = chk;
}

// ---------------- PROBE 3: B path only (L2-resident, dbuf pattern) ----------------
__global__ __launch_bounds__(256, 2)
void probe_b(const unsigned short* __restrict__ CB, float* __restrict__ sink) {
  const int tid  = threadIdx.x;
  const int lane = tid & 63;
  const int wave = tid >> 6;
  const int hi   = lane >> 4;
  const int lo   = lane & 15;
  bf16x8 bA[4][2], bB[4][2];
  auto loadB = [&](int ks, bf16x8 (&bf)[4][2]) {
    #pragma unroll
    for (int n = 0; n < 4; ++n)
      #pragma unroll
      for (int ku = 0; ku < 2; ++ku)
        bf[n][ku] = *reinterpret_cast<const bf16x8*>(
            &CB[(size_t)(wave * 64 + n * 16 + lo) * Dd + ks * BK + ku * 32 + hi * 8]);
  };
  unsigned chk = 0;
  loadB(0, bA);
  auto consume = [&](bf16x8 (&bf)[4][2]) {
    #pragma unroll
    for (int n = 0; n < 4; ++n)
      #pragma unroll
      for (int ku = 0; ku < 2; ++ku) {
        uint4 u = *reinterpret_cast<uint4*>(&bf[n][ku]);
        chk ^= u.x ^ u.y ^ u.z ^ u.w;
      }
  };
  #pragma unroll
  for (int p = 0; p < 4; ++p) {
    if (2 * p < 7) loadB(2 * p + 1, bB);
    consume(bA);
    rbar();
    if (2 * p + 1 < 7) loadB(2 * p + 2, bA);
    consume(bB);
    rbar();
  }
  float c = (float)chk;
  #pragma unroll
  for (int m = 1; m < 64; m <<= 1) c += __shfl_xor(c, m, 64);
  if ((tid & 63) == 0) sink[blockIdx.x * 4 + (tid >> 6)] = c;
}

// ---------------- PROBE 4: epilogue only (q + reduce + 67MB writes) ----------------
__global__ __launch_bounds__(256, 2)
void probe_epi(const float* __restrict__ c2g, float* __restrict__ out) {
  __shared__ float x2s[BM];
  __shared__ __align__(16) float rowp[BM][4];
  const int tid  = threadIdx.x;
  const int lane = tid & 63;
  const int wave = tid >> 6;
  const int hi   = lane >> 4;
  const int lo   = lane & 15;
  const int rbase = blockIdx.x * BM;
  if (tid < BM) x2s[tid] = 500.f + (float)tid;
  __syncthreads();
  f32x4 acc[4][4];
  #pragma unroll
  for (int m = 0; m < 4; ++m)
    #pragma unroll
    for (int n = 0; n < 4; ++n)
      #pragma unroll
      for (int r = 0; r < 4; ++r) acc[m][n][r] = (float)(lane + 3 * m + 5 * n + 7 * r);
  float c2v[4];
  #pragma unroll
  for (int n = 0; n < 4; ++n) c2v[n] = c2g[wave * 64 + n * 16 + lo];
  float rs[4][4];
  #pragma unroll
  for (int m = 0; m < 4; ++m)
    #pragma unroll
    for (int r = 0; r < 4; ++r) rs[m][r] = 0.f;
  #pragma unroll
  for (int m = 0; m < 4; ++m)
    #pragma unroll
    for (int n = 0; n < 4; ++n)
      #pragma unroll
      for (int r = 0; r < 4; ++r) {
        const int row = m * 16 + hi * 4 + r;
        float dist = fmaxf(x2s[row] + c2v[n] - 2.f * acc[m][n][r], 0.f);
        float qv = __builtin_amdgcn_rcpf(1.f + dist);
        acc[m][n][r] = qv;
        rs[m][r] += qv;
      }
  #pragma unroll
  for (int m = 0; m < 4; ++m)
    #pragma unroll
    for (int r = 0; r < 4; ++r) {
      float s = rs[m][r];
      s += __shfl_xor(s, 1); s += __shfl_xor(s, 2);
      s += __shfl_xor(s, 4); s += __shfl_xor(s, 8);
      rs[m][r] = s;
    }
  if (lo == 0) {
    #pragma unroll
    for (int m = 0; m < 4; ++m)
      #pragma unroll
      for (int r = 0; r < 4; ++r)
        rowp[m * 16 + hi * 4 + r][wave] = rs[m][r];
  }
  __syncthreads();
  #pragma unroll
  for (int m = 0; m < 4; ++m)
    #pragma unroll
    for (int n = 0; n < 4; ++n)
      #pragma unroll
      for (int r = 0; r < 4; ++r) {
        const int row = m * 16 + hi * 4 + r;
        float4 t = *reinterpret_cast<float4*>(rowp[row]);
        float ri = __builtin_amdgcn_rcpf(t.x + t.y + t.z + t.w);
        out[(size_t)(rbase + row) * Kk + wave * 64 + n * 16 + lo] = acc[m][n][r] * ri;
      }
}

// ---------------- MAIN: R3-exact best (61.8 us) ----------------
__global__ __launch_bounds__(256, 2)
void cluster_q_kernel(const float* __restrict__ X,
                      const unsigned short* __restrict__ CB,
                      const float* __restrict__ c2g,
                      float* __restrict__ out) {
  __shared__ __align__(16) char Al[2][BM * BK * 2];
  __shared__ float x2s[BM];
  __shared__ __align__(16) float rowp[BM][4];

  const int tid  = threadIdx.x;
  const int lane = tid & 63;
  const int wave = tid >> 6;
  const int hi   = lane >> 4;
  const int lo   = lane & 15;
  const int rbase = blockIdx.x * BM;
  const int arow  = tid >> 4;
  const int acolb = (tid & 15) * 8;

  f32x4 acc[4][4];
  #pragma unroll
  for (int m = 0; m < 4; ++m)
    #pragma unroll
    for (int n = 0; n < 4; ++n)
      #pragma unroll
      for (int r = 0; r < 4; ++r) acc[m][n][r] = 0.f;

  float x2p[4] = {0.f, 0.f, 0.f, 0.f};
  float4 v[2][4];
  bf16x8 bA[4][2], bB[4][2];

  auto loadG = [&](int ks) {
    #pragma unroll
    for (int it = 0; it < 4; ++it)
      v[ks & 1][it] = *reinterpret_cast<const float4*>(
          &X[(size_t)(rbase + it * 16 + arow) * Dd + ks * BK + (tid & 15) * 4]);
  };
  auto stage = [&](int ks) {
    #pragma unroll
    for (int it = 0; it < 4; ++it) {
      const int row = it * 16 + arow;
      float4 f = v[ks & 1][it];
      x2p[it] += f.x * f.x + f.y * f.y + f.z * f.z + f.w * f.w;
      uint2 p;
      p.x = ((unsigned)f2bf(f.y) << 16) | f2bf(f.x);
      p.y = ((unsigned)f2bf(f.w) << 16) | f2bf(f.z);
      const int addr = (row * 128 + acolb) ^ ((row & 7) << 4);
      *reinterpret_cast<uint2*>(&Al[ks & 1][addr]) = p;
    }
  };
  auto loadB = [&](int ks, bf16x8 (&bf)[4][2]) {
    #pragma unroll
    for (int n = 0; n < 4; ++n)
      #pragma unroll
      for (int ku = 0; ku < 2; ++ku)
        bf[n][ku] = *reinterpret_cast<const bf16x8*>(
            &CB[(size_t)(wave * 64 + n * 16 + lo) * Dd + ks * BK + ku * 32 + hi * 8]);
  };
  auto compute = [&](int ks, bf16x8 (&bf)[4][2]) {
    #pragma unroll
    for (int ku = 0; ku < 2; ++ku) {
      bf16x8 af[4];
      #pragma unroll
      for (int m = 0; m < 4; ++m) {
        const int row = m * 16 + lo;
        const int addr = (row * 128 + ku * 64 + hi * 16) ^ ((row & 7) << 4);
        af[m] = *reinterpret_cast<const bf16x8*>(&Al[ks & 1][addr]);
      }
      #pragma unroll
      for (int m = 0; m < 4; ++m)
        #pragma unroll
        for (int n = 0; n < 4; ++n)
          acc[m][n] = __builtin_amdgcn_mfma_f32_16x16x32_bf16(af[m], bf[n][ku], acc[m][n], 0, 0, 0);
    }
  };

  loadG(0);
  stage(0);
  loadG(1);
  loadB(0, bA);
  rbar();

  auto iter = [&](int ks, bf16x8 (&bcur)[4][2], bf16x8 (&bnxt)[4][2]) {
    if (ks < 7) stage(ks + 1);
    if (ks < 6) loadG(ks + 2);
    if (ks < 7) loadB(ks + 1, bnxt);
    compute(ks, bcur);
    rbar();
  };

  #pragma unroll
  for (int p = 0; p < 4; ++p) {
    iter(2 * p, bA, bB);
    iter(2 * p + 1, bB, bA);
  }

  #pragma unroll
  for (int it = 0; it < 4; ++it) {
    float s = x2p[it];
    s += __shfl_xor(s, 1); s += __shfl_xor(s, 2);
    s += __shfl_xor(s, 4); s += __shfl_xor(s, 8);
    if ((tid & 15) == 0) x2s[it * 16 + arow] = s;
  }
  __syncthreads();

  float c2v[4];
  #pragma unroll
  for (int n = 0; n < 4; ++n) c2v[n] = c2g[wave * 64 + n * 16 + lo];

  float rs[4][4];
  #pragma unroll
  for (int m = 0; m < 4; ++m)
    #pragma unroll
    for (int r = 0; r < 4; ++r) rs[m][r] = 0.f;

  #pragma unroll
  for (int m = 0; m < 4; ++m) {
    #pragma unroll
    for (int n = 0; n < 4; ++n) {
      #pragma unroll
      for (int r = 0; r < 4; ++r) {
        const int row = m * 16 + hi * 4 + r;
        float dist = x2s[row] + c2v[n] - 2.f * acc[m][n][r];
        dist = fmaxf(dist, 0.f);
        float qv = __builtin_amdgcn_rcpf(1.f + dist);
        acc[m][n][r] = qv;
        rs[m][r] += qv;
      }
    }
  }

  #pragma unroll
  for (int m = 0; m < 4; ++m)
    #pragma unroll
    for (int r = 0; r < 4; ++r) {
      float s = rs[m][r];
      s += __shfl_xor(s, 1); s += __shfl_xor(s, 2);
      s += __shfl_xor(s, 4); s += __shfl_xor(s, 8);
      rs[m][r] = s;
    }

  if (lo == 0) {
    #pragma unroll
    for (int m = 0; m < 4; ++m)
      #pragma unroll
      for (int r = 0; r < 4; ++r)
        rowp[m * 16 + hi * 4 + r][wave] = rs[m][r];
  }
  __syncthreads();

  float rinv[4][4];
  #pragma unroll
  for (int m = 0; m < 4; ++m)
    #pragma unroll
    for (int r = 0; r < 4; ++r) {
      float4 t = *reinterpret_cast<float4*>(rowp[m * 16 + hi * 4 + r]);
      rinv[m][r] = __builtin_amdgcn_rcpf(t.x + t.y + t.z + t.w);
    }

  #pragma unroll
  for (int m = 0; m < 4; ++m)
    #pragma unroll
    for (int n = 0; n < 4; ++n)
      #pragma unroll
      for (int r = 0; r < 4; ++r) {
        const int row = m * 16 + hi * 4 + r;
        out[(size_t)(rbase + row) * Kk + wave * 64 + n * 16 + lo] = acc[m][n][r] * rinv[m][r];
      }
}

extern "C" void kernel_launch(void* const* d_in, const int* in_sizes, int n_in,
                              void* d_out, int out_size, void* d_ws, size_t ws_size,
                              hipStream_t stream) {
  const float* X = reinterpret_cast<const float*>(d_in[0]);
  const float* C = reinterpret_cast<const float*>(d_in[1]);
  unsigned short* CB = reinterpret_cast<unsigned short*>(d_ws);
  float* c2 = reinterpret_cast<float*>(reinterpret_cast<char*>(d_ws) + (size_t)Kk * Dd * 2);
  float* sink = reinterpret_cast<float*>(d_ws);   // overwritten by prep afterwards

  // --- ablation probes (timed per-dispatch via rocprof; sinks later overwritten) ---
  probe_g  <<<Nn / BM, 256, 0, stream>>>(X, sink);
  probe_a  <<<Nn / BM, 256, 0, stream>>>(X, sink);
  probe_b  <<<Nn / BM, 256, 0, stream>>>(CB, sink);           // same addr/traffic pattern as main
  probe_epi<<<Nn / BM, 256, 0, stream>>>(c2, reinterpret_cast<float*>(d_out)); // d_out fully rewritten below

  // --- real pipeline (R3-exact) ---
  prep_clusters_kernel<<<Kk, 64, 0, stream>>>(C, CB, c2);
  cluster_q_kernel<<<Nn / BM, 256, 0, stream>>>(X, CB, c2, reinterpret_cast<float*>(d_out));
}

// Round 11
// 128.086 us; speedup vs baseline: 1.0957x; 1.0957x over previous
//
#include <hip/hip_runtime.h>
#include <hip/hip_bf16.h>

typedef short bf16x8 __attribute__((ext_vector_type(8)));
typedef float f32x4 __attribute__((ext_vector_type(4)));

constexpr int Nn = 65536;
constexpr int Kk = 256;
constexpr int Dd = 512;
constexpr int BMW = 32;              // rows per block (shared by 4 waves)

static __device__ __forceinline__ unsigned short f2bf(float f) {
  __hip_bfloat16 h = __float2bfloat16(f);
  return *reinterpret_cast<unsigned short*>(&h);
}

static __device__ __forceinline__ bf16x8 pack8(float4 u, float4 v) {
  union { unsigned u32[4]; bf16x8 v8; } r;
  r.u32[0] = ((unsigned)f2bf(u.y) << 16) | f2bf(u.x);
  r.u32[1] = ((unsigned)f2bf(u.w) << 16) | f2bf(u.z);
  r.u32[2] = ((unsigned)f2bf(v.y) << 16) | f2bf(v.x);
  r.u32[3] = ((unsigned)f2bf(v.w) << 16) | f2bf(v.z);
  return r.v8;
}

static __device__ __forceinline__ void fence() { asm volatile("" ::: "memory"); }

// Clusters -> bf16 row-major [K][D] + c2[k] = sum_d C[k][d]^2 (fp32).
__global__ __launch_bounds__(64)
void prep_clusters_kernel(const float* __restrict__ C,
                          unsigned short* __restrict__ CB,
                          float* __restrict__ c2) {
  const int k = blockIdx.x;
  const int t = threadIdx.x;
  const float* row = C + (size_t)k * Dd;
  float4 a = *reinterpret_cast<const float4*>(row + t * 8);
  float4 b = *reinterpret_cast<const float4*>(row + t * 8 + 4);
  float s = a.x * a.x + a.y * a.y + a.z * a.z + a.w * a.w
          + b.x * b.x + b.y * b.y + b.z * b.z + b.w * b.w;
  uint4 p;
  p.x = ((unsigned)f2bf(a.y) << 16) | f2bf(a.x);
  p.y = ((unsigned)f2bf(a.w) << 16) | f2bf(a.z);
  p.z = ((unsigned)f2bf(b.y) << 16) | f2bf(b.x);
  p.w = ((unsigned)f2bf(b.w) << 16) | f2bf(b.z);
  *reinterpret_cast<uint4*>(CB + (size_t)k * Dd + t * 8) = p;
  #pragma unroll
  for (int m = 1; m < 64; m <<= 1) s += __shfl_xor(s, m, 64);
  if (t == 0) c2[k] = s;
}

// Barrier-free GEMM: 256 threads (4 independent waves). Block = 32 rows x 256 cols;
// wave w owns cols [64w, 64w+64). ALL operands global->reg (no LDS, no staging, no
// K-loop barriers): A fp32 coalesced (128B/row across hi-groups), packed bf16 in-loop
// (x2 free); B bf16 from L2-resident CB. Reg double-buffer, 16 unrolled k-steps.
// Little's law: each wave holds ~8KB outstanding; even 8 waves/CU = 64KB >> the
// ~23KB/CU needed for 6+ TB/s (fillBuffer regime: thin waves, zero coupling).
__global__ __launch_bounds__(256)
void cluster_q_kernel(const float* __restrict__ X,
                      const unsigned short* __restrict__ CB,
                      const float* __restrict__ c2g,
                      float* __restrict__ out) {
  __shared__ __align__(16) float rowp[BMW][4];

  const int tid  = threadIdx.x;
  const int lane = tid & 63;
  const int w    = tid >> 6;
  const int hi   = lane >> 4;   // 0..3
  const int lo   = lane & 15;   // 0..15
  const int rb   = blockIdx.x * BMW;

  const float* ar0 = X + (size_t)(rb + lo) * Dd;        // m=0 row for this lane
  const float* ar1 = X + (size_t)(rb + 16 + lo) * Dd;   // m=1 row
  const unsigned short* cbp = CB + (size_t)(w * 64 + lo) * Dd;  // n stride = 16*Dd

  f32x4 acc[2][4];
  #pragma unroll
  for (int m = 0; m < 2; ++m)
    #pragma unroll
    for (int n = 0; n < 4; ++n)
      #pragma unroll
      for (int r = 0; r < 4; ++r) acc[m][n][r] = 0.f;

  float4  a[2][2][2];   // [parity][m][half]: fp32 A frags, 1 k-step ahead
  bf16x8  b[2][4];      // [parity][n]: B frags
  float   x2p[2] = {0.f, 0.f};

  auto loadA = [&](int ks) {
    const int p = ks & 1;
    const int o = ks * 32 + hi * 8;
    a[p][0][0] = *reinterpret_cast<const float4*>(ar0 + o);
    a[p][0][1] = *reinterpret_cast<const float4*>(ar0 + o + 4);
    a[p][1][0] = *reinterpret_cast<const float4*>(ar1 + o);
    a[p][1][1] = *reinterpret_cast<const float4*>(ar1 + o + 4);
  };
  auto loadB = [&](int ks) {
    const int p = ks & 1;
    #pragma unroll
    for (int n = 0; n < 4; ++n)
      b[p][n] = *reinterpret_cast<const bf16x8*>(cbp + (size_t)n * 16 * Dd + ks * 32 + hi * 8);
  };
  auto compute = [&](int ks) {
    const int p = ks & 1;
    bf16x8 af[2];
    #pragma unroll
    for (int m = 0; m < 2; ++m) {
      float4 f0 = a[p][m][0], f1 = a[p][m][1];
      x2p[m] += f0.x * f0.x + f0.y * f0.y + f0.z * f0.z + f0.w * f0.w
              + f1.x * f1.x + f1.y * f1.y + f1.z * f1.z + f1.w * f1.w;
      af[m] = pack8(f0, f1);
    }
    #pragma unroll
    for (int m = 0; m < 2; ++m)
      #pragma unroll
      for (int n = 0; n < 4; ++n)
        acc[m][n] = __builtin_amdgcn_mfma_f32_16x16x32_bf16(af[m], b[p][n], acc[m][n], 0, 0, 0);
  };

  loadA(0);
  loadB(0);
  fence();

  #pragma unroll
  for (int ks = 0; ks < 16; ++ks) {
    if (ks < 15) { loadA(ks + 1); loadB(ks + 1); fence(); }  // issue-before-consume:
    compute(ks);  // waits only loads(ks); loads(ks+1) stay in flight (in-order vmcnt)
  }

  // x2: lane covered k = {ks*32 + hi*8 ..+8} -> sum over the 4 hi-groups gives the
  // full row sum for rows {lo, 16+lo} (uniform across hi after the reduce).
  float x2row[2];
  #pragma unroll
  for (int m = 0; m < 2; ++m) {
    float s = x2p[m];
    s += __shfl_xor(s, 16);
    s += __shfl_xor(s, 32);
    x2row[m] = s;
  }

  float c2v[4];
  #pragma unroll
  for (int n = 0; n < 4; ++n) c2v[n] = c2g[w * 64 + n * 16 + lo];

  // q = 1/(1+dist) (ALPHA=1); v_rcp_f32 ~1ulp (q<=1 -> abs err ~1e-7 << 1e-4 thr).
  float rs[2][4];
  #pragma unroll
  for (int m = 0; m < 2; ++m)
    #pragma unroll
    for (int r = 0; r < 4; ++r) rs[m][r] = 0.f;

  #pragma unroll
  for (int m = 0; m < 2; ++m) {
    #pragma unroll
    for (int r = 0; r < 4; ++r) {
      const float x2v = __shfl(x2row[m], hi * 4 + r);   // row m*16+hi*4+r
      #pragma unroll
      for (int n = 0; n < 4; ++n) {
        float dist = fmaxf(x2v + c2v[n] - 2.f * acc[m][n][r], 0.f);
        float qv = __builtin_amdgcn_rcpf(1.f + dist);
        acc[m][n][r] = qv;
        rs[m][r] += qv;
      }
    }
  }

  // Row sums: reduce over the 16 col-lanes, then across the 4 waves via LDS.
  #pragma unroll
  for (int m = 0; m < 2; ++m)
    #pragma unroll
    for (int r = 0; r < 4; ++r) {
      float s = rs[m][r];
      s += __shfl_xor(s, 1); s += __shfl_xor(s, 2);
      s += __shfl_xor(s, 4); s += __shfl_xor(s, 8);
      rs[m][r] = s;
    }
  if (lo == 0) {
    #pragma unroll
    for (int m = 0; m < 2; ++m)
      #pragma unroll
      for (int r = 0; r < 4; ++r) rowp[m * 16 + hi * 4 + r][w] = rs[m][r];
  }
  __syncthreads();

  #pragma unroll
  for (int m = 0; m < 2; ++m)
    #pragma unroll
    for (int r = 0; r < 4; ++r) {
      const int row = m * 16 + hi * 4 + r;
      float4 t = *reinterpret_cast<float4*>(rowp[row]);
      const float ri = __builtin_amdgcn_rcpf(t.x + t.y + t.z + t.w);
      #pragma unroll
      for (int n = 0; n < 4; ++n)
        out[(size_t)(rb + row) * Kk + w * 64 + n * 16 + lo] = acc[m][n][r] * ri;
    }
}

extern "C" void kernel_launch(void* const* d_in, const int* in_sizes, int n_in,
                              void* d_out, int out_size, void* d_ws, size_t ws_size,
                              hipStream_t stream) {
  const float* X = reinterpret_cast<const float*>(d_in[0]);
  const float* C = reinterpret_cast<const float*>(d_in[1]);
  unsigned short* CB = reinterpret_cast<unsigned short*>(d_ws);           // 256 KB bf16 clusters
  float* c2 = reinterpret_cast<float*>(reinterpret_cast<char*>(d_ws) + (size_t)Kk * Dd * 2);
  prep_clusters_kernel<<<Kk, 64, 0, stream>>>(C, CB, c2);
  cluster_q_kernel<<<Nn / BMW, 256, 0, stream>>>(X, CB, c2, reinterpret_cast<float*>(d_out));
}